// Round 6
// baseline (10786.797 us; speedup 1.0000x reference)
//
#include <hip/hip_runtime.h>
#include <hip/hip_bf16.h>

#define NREL 5
#define HDIM 256
#define NDST 100000
#define KTOT 1536  // (1+NREL)*HDIM

typedef __attribute__((ext_vector_type(8))) short short8;
typedef __attribute__((ext_vector_type(4))) float f32x4;

__device__ __forceinline__ unsigned short f2bf(float f) {
  unsigned int u = __builtin_bit_cast(unsigned int, f);
  u += 0x7fffu + ((u >> 16) & 1u);
  return (unsigned short)(u >> 16);
}

// Build WT[cv][n][k] (bf16 bits), cv = L*3+c, k<256 -> root[L][c][k][n], else W[L][c][r][kk][n]
__global__ void prep_wt(const float* __restrict__ W, const float* __restrict__ root,
                        unsigned short* __restrict__ WT) {
  long long i = (long long)blockIdx.x * blockDim.x + threadIdx.x;
  const long long total = 9LL * HDIM * KTOT;
  if (i >= total) return;
  int cv = (int)(i / (HDIM * KTOT));
  int rem = (int)(i % (HDIM * KTOT));
  int n = rem / KTOT;
  int k = rem % KTOT;
  float v;
  if (k < HDIM) {
    v = root[((long long)cv * HDIM + k) * HDIM + n];
  } else {
    int r = (k - HDIM) >> 8;
    int kk = (k - HDIM) & 255;
    v = W[(((long long)cv * NREL + r) * HDIM + kk) * HDIM + n];
  }
  WT[i] = f2bf(v);
}

__global__ void count_edges(const int* __restrict__ dst, const int* __restrict__ et,
                            int E, float* __restrict__ cnt) {
  int e = blockIdx.x * 256 + threadIdx.x;
  if (e < E) unsafeAtomicAdd(&cnt[(long long)et[e] * NDST + dst[e]], 1.0f);
}

__global__ void make_rcp(const float* __restrict__ cnt, float* __restrict__ rcp) {
  int i = blockIdx.x * 256 + threadIdx.x;
  if (i < NREL * NDST) rcp[i] = 1.0f / fmaxf(cnt[i], 1.0f);
}

// PRIMARY: one wave per edge, scatter into agg[et][dst]; lane 0 bumps cnt.
__global__ void scatter_edges(const float* __restrict__ xsrc, const int* __restrict__ src,
                              const int* __restrict__ dst, const int* __restrict__ et,
                              int E, float* __restrict__ agg, float* __restrict__ cnt) {
  int gtid = blockIdx.x * blockDim.x + threadIdx.x;
  int wid = gtid >> 6;
  int lane = threadIdx.x & 63;
  int nw = (gridDim.x * blockDim.x) >> 6;
  for (int e = wid; e < E; e += nw) {
    int s = __builtin_amdgcn_readfirstlane(src[e]);
    int d = __builtin_amdgcn_readfirstlane(dst[e]);
    int r = __builtin_amdgcn_readfirstlane(et[e]);
    float4 v = ((const float4*)(xsrc + (long long)s * HDIM))[lane];
    long long slot = (long long)r * NDST + d;
    if (lane == 0) unsafeAtomicAdd(&cnt[slot], 1.0f);
    float* arow = agg + slot * HDIM + lane * 4;
    unsafeAtomicAdd(arow + 0, v.x);
    unsafeAtomicAdd(arow + 1, v.y);
    unsafeAtomicAdd(arow + 2, v.z);
    unsafeAtomicAdd(arow + 3, v.w);
  }
}

// FALLBACK: scatter only edges of relation `rel` into single-relation aggR.
__global__ void scatter_edges_rel(const float* __restrict__ xsrc, const int* __restrict__ src,
                                  const int* __restrict__ dst, const int* __restrict__ et,
                                  int E, int rel, float* __restrict__ aggR) {
  int gtid = blockIdx.x * blockDim.x + threadIdx.x;
  int wid = gtid >> 6;
  int lane = threadIdx.x & 63;
  int nw = (gridDim.x * blockDim.x) >> 6;
  for (int e = wid; e < E; e += nw) {
    int r = __builtin_amdgcn_readfirstlane(et[e]);
    if (r != rel) continue;
    int s = __builtin_amdgcn_readfirstlane(src[e]);
    int d = __builtin_amdgcn_readfirstlane(dst[e]);
    float4 v = ((const float4*)(xsrc + (long long)s * HDIM))[lane];
    float* arow = aggR + (long long)d * HDIM + lane * 4;
    unsafeAtomicAdd(arow + 0, v.x);
    unsafeAtomicAdd(arow + 1, v.y);
    unsafeAtomicAdd(arow + 2, v.z);
    unsafeAtomicAdd(arow + 3, v.w);
  }
}

// PRIMARY GEMM: out[m][n] = lrelu( bias[n] + sum_k Avirt[m][k] * Wcat[k][n] ), K=1536 virtual A
__global__ __launch_bounds__(256) void rgcn_gemm(
    const float* __restrict__ xdst, const float* __restrict__ agg,
    const float* __restrict__ rcp, const unsigned short* __restrict__ WTc,
    const float* __restrict__ biasc, float* __restrict__ out) {
  __shared__ __align__(16) char AsRaw[64 * 128];    // 64 rows x 64 bf16 (swizzled)
  __shared__ __align__(16) char BsRaw[256 * 128];   // 256 n-rows x 64 bf16 (swizzled)

  const int m0 = blockIdx.x * 64;
  const int tid = threadIdx.x;
  const int w = tid >> 6;
  const int lane = tid & 63;
  const int fr = lane & 15;
  const int fk = lane >> 4;

  f32x4 acc[4][4] = {};

  for (int k0 = 0; k0 < KTOT; k0 += 64) {
    __syncthreads();
    const int region = k0 >> 8;
    const int koff = k0 & 255;
#pragma unroll
    for (int i = 0; i < 4; ++i) {               // stage A (fp32 -> bf16)
      int idx = tid + 256 * i;
      int row = idx >> 4;
      int ch = idx & 15;
      int gm = m0 + row;
      float4 v = make_float4(0.f, 0.f, 0.f, 0.f);
      float scale = 1.0f;
      if (gm < NDST) {
        if (region == 0) {
          v = *(const float4*)(xdst + (long long)gm * HDIM + koff + ch * 4);
        } else {
          int r = region - 1;
          v = *(const float4*)(agg + ((long long)r * NDST + gm) * HDIM + koff + ch * 4);
          scale = rcp[(long long)r * NDST + gm];
        }
      }
      ushort4 b;
      b.x = f2bf(v.x * scale);
      b.y = f2bf(v.y * scale);
      b.z = f2bf(v.z * scale);
      b.w = f2bf(v.w * scale);
      int u = ch >> 1;
      int su = u ^ (row & 7);
      *(ushort4*)(AsRaw + row * 128 + su * 16 + (ch & 1) * 8) = b;
    }
#pragma unroll
    for (int i = 0; i < 8; ++i) {               // stage B
      int idx = tid + 256 * i;
      int row = idx >> 3;
      int u = idx & 7;
      uint4 wv = *(const uint4*)(WTc + (long long)row * KTOT + k0 + u * 8);
      int su = u ^ (row & 7);
      *(uint4*)(BsRaw + row * 128 + su * 16) = wv;
    }
    __syncthreads();
#pragma unroll
    for (int kk = 0; kk < 2; ++kk) {
      short8 a[4], b[4];
      int u = kk * 4 + fk;
#pragma unroll
      for (int mt = 0; mt < 4; ++mt) {
        int rowa = mt * 16 + fr;
        a[mt] = *(const short8*)(AsRaw + rowa * 128 + ((u ^ (rowa & 7)) * 16));
      }
#pragma unroll
      for (int nt = 0; nt < 4; ++nt) {
        int rowb = w * 64 + nt * 16 + fr;
        b[nt] = *(const short8*)(BsRaw + rowb * 128 + ((u ^ (rowb & 7)) * 16));
      }
#pragma unroll
      for (int mt = 0; mt < 4; ++mt)
#pragma unroll
        for (int nt = 0; nt < 4; ++nt)
          acc[mt][nt] = __builtin_amdgcn_mfma_f32_16x16x32_bf16(a[mt], b[nt], acc[mt][nt], 0, 0, 0);
    }
  }

#pragma unroll
  for (int nt = 0; nt < 4; ++nt) {
    int col = w * 64 + nt * 16 + fr;
    float bv = biasc[col];
#pragma unroll
    for (int mt = 0; mt < 4; ++mt) {
#pragma unroll
      for (int j = 0; j < 4; ++j) {
        int grow = m0 + mt * 16 + fk * 4 + j;
        if (grow < NDST) {
          float v = acc[mt][nt][j] + bv;
          v = v > 0.f ? v : 0.01f * v;
          out[(long long)grow * HDIM + col] = v;
        }
      }
    }
  }
}

// FALLBACK GEMM: K=256 pass. out = [out +] A(*scale) @ WTbase + [bias]; optional lrelu.
// WTbase row n at WTbase + n*KTOT (region k-offset pre-added by caller).
__global__ __launch_bounds__(256) void rgcn_gemm_k256(
    const float* __restrict__ A, const float* __restrict__ scale,
    const unsigned short* __restrict__ WTbase, const float* __restrict__ biasc,
    float* __restrict__ out, int accumulate, int activate) {
  __shared__ __align__(16) char AsRaw[64 * 128];
  __shared__ __align__(16) char BsRaw[256 * 128];

  const int m0 = blockIdx.x * 64;
  const int tid = threadIdx.x;
  const int w = tid >> 6;
  const int lane = tid & 63;
  const int fr = lane & 15;
  const int fk = lane >> 4;

  f32x4 acc[4][4] = {};

  for (int k0 = 0; k0 < 256; k0 += 64) {
    __syncthreads();
#pragma unroll
    for (int i = 0; i < 4; ++i) {
      int idx = tid + 256 * i;
      int row = idx >> 4;
      int ch = idx & 15;
      int gm = m0 + row;
      float4 v = make_float4(0.f, 0.f, 0.f, 0.f);
      float sc = 1.0f;
      if (gm < NDST) {
        v = *(const float4*)(A + (long long)gm * HDIM + k0 + ch * 4);
        if (scale) sc = scale[gm];
      }
      ushort4 b;
      b.x = f2bf(v.x * sc);
      b.y = f2bf(v.y * sc);
      b.z = f2bf(v.z * sc);
      b.w = f2bf(v.w * sc);
      int u = ch >> 1;
      int su = u ^ (row & 7);
      *(ushort4*)(AsRaw + row * 128 + su * 16 + (ch & 1) * 8) = b;
    }
#pragma unroll
    for (int i = 0; i < 8; ++i) {
      int idx = tid + 256 * i;
      int row = idx >> 3;
      int u = idx & 7;
      uint4 wv = *(const uint4*)(WTbase + (long long)row * KTOT + k0 + u * 8);
      int su = u ^ (row & 7);
      *(uint4*)(BsRaw + row * 128 + su * 16) = wv;
    }
    __syncthreads();
#pragma unroll
    for (int kk = 0; kk < 2; ++kk) {
      short8 a[4], b[4];
      int u = kk * 4 + fk;
#pragma unroll
      for (int mt = 0; mt < 4; ++mt) {
        int rowa = mt * 16 + fr;
        a[mt] = *(const short8*)(AsRaw + rowa * 128 + ((u ^ (rowa & 7)) * 16));
      }
#pragma unroll
      for (int nt = 0; nt < 4; ++nt) {
        int rowb = w * 64 + nt * 16 + fr;
        b[nt] = *(const short8*)(BsRaw + rowb * 128 + ((u ^ (rowb & 7)) * 16));
      }
#pragma unroll
      for (int mt = 0; mt < 4; ++mt)
#pragma unroll
        for (int nt = 0; nt < 4; ++nt)
          acc[mt][nt] = __builtin_amdgcn_mfma_f32_16x16x32_bf16(a[mt], b[nt], acc[mt][nt], 0, 0, 0);
    }
  }

#pragma unroll
  for (int nt = 0; nt < 4; ++nt) {
    int col = w * 64 + nt * 16 + fr;
    float bv = biasc ? biasc[col] : 0.0f;
#pragma unroll
    for (int mt = 0; mt < 4; ++mt) {
#pragma unroll
      for (int j = 0; j < 4; ++j) {
        int grow = m0 + mt * 16 + fk * 4 + j;
        if (grow < NDST) {
          long long o = (long long)grow * HDIM + col;
          float v = acc[mt][nt][j] + bv;
          if (accumulate) v += out[o];
          if (activate) v = v > 0.f ? v : 0.01f * v;
          out[o] = v;
        }
      }
    }
  }
}

extern "C" void kernel_launch(void* const* d_in, const int* in_sizes, int n_in,
                              void* d_out, int out_size, void* d_ws, size_t ws_size,
                              hipStream_t stream) {
  const float* xv = (const float*)d_in[1];
  const float* xs = (const float*)d_in[2];
  const float* W = (const float*)d_in[5];
  const float* root = (const float*)d_in[6];
  const float* bias = (const float*)d_in[7];
  const int* srcC = (const int*)d_in[8];
  const int* dstC = (const int*)d_in[9];
  const int* etC = (const int*)d_in[10];
  const int* srcV = (const int*)d_in[11];
  const int* dstV = (const int*)d_in[12];
  const int* etV = (const int*)d_in[13];
  const int* srcS = (const int*)d_in[14];
  const int* dstS = (const int*)d_in[15];
  const int* etS = (const int*)d_in[16];

  const size_t AGG_FULL = (size_t)NREL * NDST * HDIM * 4;   // 512 MB
  const size_t AGG_ONE = (size_t)NDST * HDIM * 4;           // 102.4 MB
  const size_t CNT_B = (size_t)NREL * NDST * 4;             // 2 MB
  const size_t WT_B = 9LL * HDIM * KTOT * 2;                // 7.08 MB

  float* outM = (float*)d_out;
  float* outF = outM + (long long)NDST * HDIM;
  float* outL = outF + (long long)NDST * HDIM;
  float* pM = (float*)d_in[0];   // layer-1 ping buffers (harness restores inputs per call)
  float* pF = (float*)d_in[3];
  float* pL = (float*)d_in[4];

  const int Es[3] = { 320000, 160000, 160000 };
  const int* srca[3] = { srcC, srcV, srcS };
  const int* dsta[3] = { dstC, dstV, dstS };
  const int* eta[3]  = { etC, etV, etS };

  char* ws = (char*)d_ws;

  if (ws_size >= AGG_FULL + 2 * CNT_B + WT_B) {
    // ---------- PRIMARY (523 MB workspace) ----------
    float* agg = (float*)ws;
    float* cnt = (float*)(ws + AGG_FULL);
    float* rcp = (float*)(ws + AGG_FULL + CNT_B);
    unsigned short* WT = (unsigned short*)(ws + AGG_FULL + 2 * CNT_B);

    prep_wt<<<(int)((9LL * HDIM * KTOT + 255) / 256), 256, 0, stream>>>(W, root, WT);

    const float* XM = (const float*)d_in[0];
    const float* XF = (const float*)d_in[3];
    const float* XL = (const float*)d_in[4];
    for (int L = 0; L < 3; ++L) {
      float *oM, *oF, *oL;
      if (L == 1) { oM = pM; oF = pF; oL = pL; }
      else        { oM = outM; oF = outF; oL = outL; }
      const float* xsrcs[3] = { XM, xv, xs };
      const float* xdsts[3] = { XM, XF, XL };
      float* outs[3] = { oM, oF, oL };
      for (int c = 0; c < 3; ++c) {
        int cv = L * 3 + c;
        hipMemsetAsync(agg, 0, AGG_FULL, stream);
        hipMemsetAsync(cnt, 0, CNT_B, stream);
        scatter_edges<<<2048, 256, 0, stream>>>(xsrcs[c], srca[c], dsta[c], eta[c], Es[c], agg, cnt);
        make_rcp<<<(NREL * NDST + 255) / 256, 256, 0, stream>>>(cnt, rcp);
        rgcn_gemm<<<(NDST + 63) / 64, 256, 0, stream>>>(
            xdsts[c], agg, rcp, WT + (long long)cv * HDIM * KTOT, bias + cv * HDIM, outs[c]);
      }
      XM = oM; XF = oF; XL = oL;
    }
  } else if (ws_size >= AGG_ONE + 2 * CNT_B + WT_B) {
    // ---------- FALLBACK (113.5 MB workspace): per-relation aggregation ----------
    float* aggR = (float*)ws;
    float* cnt = (float*)(ws + AGG_ONE);
    float* rcp = (float*)(ws + AGG_ONE + CNT_B);
    unsigned short* WT = (unsigned short*)(ws + AGG_ONE + 2 * CNT_B);

    prep_wt<<<(int)((9LL * HDIM * KTOT + 255) / 256), 256, 0, stream>>>(W, root, WT);

    const float* XM = (const float*)d_in[0];
    const float* XF = (const float*)d_in[3];
    const float* XL = (const float*)d_in[4];
    for (int L = 0; L < 3; ++L) {
      float *oM, *oF, *oL;
      if (L == 1) { oM = pM; oF = pF; oL = pL; }
      else        { oM = outM; oF = outF; oL = outL; }
      const float* xsrcs[3] = { XM, xv, xs };
      const float* xdsts[3] = { XM, XF, XL };
      float* outs[3] = { oM, oF, oL };
      for (int c = 0; c < 3; ++c) {
        int cv = L * 3 + c;
        const unsigned short* WTcv = WT + (long long)cv * HDIM * KTOT;
        hipMemsetAsync(cnt, 0, CNT_B, stream);
        count_edges<<<(Es[c] + 255) / 256, 256, 0, stream>>>(dsta[c], eta[c], Es[c], cnt);
        make_rcp<<<(NREL * NDST + 255) / 256, 256, 0, stream>>>(cnt, rcp);
        // root pass: out = xdst @ root + bias (raw fp32)
        rgcn_gemm_k256<<<(NDST + 63) / 64, 256, 0, stream>>>(
            xdsts[c], nullptr, WTcv, bias + cv * HDIM, outs[c], 0, 0);
        for (int r = 0; r < NREL; ++r) {
          hipMemsetAsync(aggR, 0, AGG_ONE, stream);
          scatter_edges_rel<<<2048, 256, 0, stream>>>(xsrcs[c], srca[c], dsta[c], eta[c],
                                                      Es[c], r, aggR);
          rgcn_gemm_k256<<<(NDST + 63) / 64, 256, 0, stream>>>(
              aggR, rcp + (long long)r * NDST, WTcv + 256 * (r + 1), nullptr,
              outs[c], 1, (r == NREL - 1) ? 1 : 0);
        }
      }
      XM = oM; XF = oF; XL = oL;
    }
  } else {
    // ---------- DIAGNOSTIC: workspace too small for any path ----------
    hipMemsetAsync(d_out, 0, (size_t)out_size * 4, stream);
  }
}